// Round 1
// baseline (370.723 us; speedup 1.0000x reference)
//
#include <hip/hip_runtime.h>

// PrototypeLoss: loss = mean_i sum_d (features[i,d] - prototypes[labels[i],d])^2
// N=131072, D=512, C=1000. Output: single fp32 scalar (shape (1,1)).
//
// Memory-bound on the features stream (256 MiB fp32). Strategy:
//  - grid-stride over flat float4 indices of features (coalesced 16B/lane)
//  - prototypes (2 MiB) and labels (512 KiB) stay hot in L2
//  - per-thread fp32 acc -> wave64 shuffle reduce -> block LDS reduce
//  - one atomicAdd(partial / N) per block into d_out[0]
//  - d_out is poisoned 0xAA each launch: zero it with a tiny kernel first
//    (same stream => ordered; graph-capture safe, no hipMemset needed)

constexpr int N_ROWS = 131072;
constexpr int DIM    = 512;
constexpr int D4     = DIM / 4;   // 128 float4 per row
constexpr int BLOCK  = 256;
constexpr int GRID   = 2048;      // 8 blocks/CU on 256 CUs

__global__ void zero_out_kernel(float* out) { out[0] = 0.0f; }

__global__ __launch_bounds__(BLOCK) void proto_loss_kernel(
    const float4* __restrict__ features,    // N_ROWS * D4 float4
    const int*    __restrict__ labels,      // N_ROWS int32 (harness passes integer as int)
    const float4* __restrict__ prototypes,  // C * D4 float4
    float* __restrict__ out)
{
    const long long total  = (long long)N_ROWS * D4;  // 16,777,216 float4
    const long long stride = (long long)GRID * BLOCK;
    long long idx = (long long)blockIdx.x * BLOCK + threadIdx.x;

    float acc = 0.0f;
    for (; idx < total; idx += stride) {
        const int row = (int)(idx >> 7);        // idx / D4
        const int c4  = (int)(idx & (D4 - 1));  // idx % D4
        const int lab = labels[row];            // L2-hot broadcast-ish load
        const float4 f = features[idx];
        const float4 p = prototypes[lab * D4 + c4];
        const float dx = f.x - p.x;
        const float dy = f.y - p.y;
        const float dz = f.z - p.z;
        const float dw = f.w - p.w;
        acc += dx * dx + dy * dy + dz * dz + dw * dw;
    }

    // wave64 butterfly reduce
    #pragma unroll
    for (int off = 32; off > 0; off >>= 1)
        acc += __shfl_down(acc, off, 64);

    __shared__ float wave_sums[BLOCK / 64];
    const int lane = threadIdx.x & 63;
    const int wid  = threadIdx.x >> 6;
    if (lane == 0) wave_sums[wid] = acc;
    __syncthreads();

    if (threadIdx.x == 0) {
        float s = 0.0f;
        #pragma unroll
        for (int w = 0; w < BLOCK / 64; ++w) s += wave_sums[w];
        atomicAdd(out, s * (1.0f / (float)N_ROWS));
    }
}

extern "C" void kernel_launch(void* const* d_in, const int* in_sizes, int n_in,
                              void* d_out, int out_size, void* d_ws, size_t ws_size,
                              hipStream_t stream) {
    const float4* features   = (const float4*)d_in[0];
    const int*    labels     = (const int*)d_in[1];
    const float4* prototypes = (const float4*)d_in[2];
    float* out = (float*)d_out;

    zero_out_kernel<<<1, 1, 0, stream>>>(out);
    proto_loss_kernel<<<GRID, BLOCK, 0, stream>>>(features, labels, prototypes, out);
}

// Round 2
// 339.286 us; speedup vs baseline: 1.0927x; 1.0927x over previous
//
#include <hip/hip_runtime.h>

// PrototypeLoss: loss = mean_i sum_d (features[i,d] - prototypes[labels[i],d])^2
// N=131072, D=512, C=1000. Output: single fp32 scalar.
//
// Row-per-wave structure:
//  - wave id made wave-uniform via readfirstlane -> labels[row] compiles to a
//    scalar load (s_load), prototype row base becomes SGPR + lane offset
//  - each lane handles float4 columns {lane, lane+64} of its wave's row
//    (64 lanes x 2 float4 = 128 float4 = full D=512 row, fully coalesced)
//  - features loaded nontemporal (streamed once, 256 MiB >> L2) so the 2 MiB
//    prototype table stays L2-resident
//  - deterministic two-stage reduction: block partials -> d_ws -> tiny reduce
//    kernel (no atomics, no zero-init kernel)

typedef float fvec4 __attribute__((ext_vector_type(4)));

constexpr int N_ROWS = 131072;
constexpr int D4     = 128;                   // float4 per row (D = 512)
constexpr int BLOCK  = 256;                   // 4 waves/block
constexpr int GRID   = 2048;                  // 8 blocks/CU
constexpr int WAVES  = GRID * (BLOCK / 64);   // 8192 waves
constexpr int ROWS_PER_WAVE = N_ROWS / WAVES; // 16 contiguous rows per wave

__global__ __launch_bounds__(BLOCK) void proto_loss_main(
    const fvec4* __restrict__ features,    // N_ROWS * D4
    const int*   __restrict__ labels,      // N_ROWS
    const fvec4* __restrict__ prototypes,  // C * D4
    float* __restrict__ partials)          // GRID floats in d_ws
{
    const int lane = threadIdx.x & 63;
    const int wid  = threadIdx.x >> 6;
    // force wave-uniform wave index into an SGPR
    const int wave = __builtin_amdgcn_readfirstlane(blockIdx.x * (BLOCK / 64) + wid);
    const int row0 = wave * ROWS_PER_WAVE;

    float acc = 0.0f;
    #pragma unroll 4
    for (int i = 0; i < ROWS_PER_WAVE; ++i) {
        const int row = row0 + i;                       // SGPR
        const int lab = labels[row];                    // scalar load (uniform addr)
        const long long fbase = (long long)row * D4;
        const fvec4 f0 = __builtin_nontemporal_load(features + fbase + lane);
        const fvec4 f1 = __builtin_nontemporal_load(features + fbase + 64 + lane);
        const fvec4* prow = prototypes + lab * D4;      // SGPR base
        const fvec4 p0 = prow[lane];
        const fvec4 p1 = prow[lane + 64];

        fvec4 d0 = f0 - p0;
        fvec4 d1 = f1 - p1;
        acc += d0.x * d0.x + d0.y * d0.y + d0.z * d0.z + d0.w * d0.w
             + d1.x * d1.x + d1.y * d1.y + d1.z * d1.z + d1.w * d1.w;
    }

    // wave64 reduce
    #pragma unroll
    for (int off = 32; off > 0; off >>= 1)
        acc += __shfl_down(acc, off, 64);

    __shared__ float wave_sums[BLOCK / 64];
    if (lane == 0) wave_sums[wid] = acc;
    __syncthreads();

    if (threadIdx.x == 0) {
        float s = 0.0f;
        #pragma unroll
        for (int w = 0; w < BLOCK / 64; ++w) s += wave_sums[w];
        partials[blockIdx.x] = s;
    }
}

__global__ __launch_bounds__(BLOCK) void proto_loss_reduce(
    const float* __restrict__ partials, float* __restrict__ out)
{
    float s = 0.0f;
    for (int i = threadIdx.x; i < GRID; i += BLOCK)
        s += partials[i];

    #pragma unroll
    for (int off = 32; off > 0; off >>= 1)
        s += __shfl_down(s, off, 64);

    __shared__ float wave_sums[BLOCK / 64];
    const int lane = threadIdx.x & 63;
    const int wid  = threadIdx.x >> 6;
    if (lane == 0) wave_sums[wid] = s;
    __syncthreads();

    if (threadIdx.x == 0) {
        float t = 0.0f;
        #pragma unroll
        for (int w = 0; w < BLOCK / 64; ++w) t += wave_sums[w];
        out[0] = t * (1.0f / (float)N_ROWS);
    }
}

extern "C" void kernel_launch(void* const* d_in, const int* in_sizes, int n_in,
                              void* d_out, int out_size, void* d_ws, size_t ws_size,
                              hipStream_t stream) {
    const fvec4* features   = (const fvec4*)d_in[0];
    const int*   labels     = (const int*)d_in[1];
    const fvec4* prototypes = (const fvec4*)d_in[2];
    float* partials = (float*)d_ws;   // GRID * 4 bytes of scratch
    float* out      = (float*)d_out;

    proto_loss_main<<<GRID, BLOCK, 0, stream>>>(features, labels, prototypes, partials);
    proto_loss_reduce<<<1, BLOCK, 0, stream>>>(partials, out);
}